// Round 13
// baseline (493.241 us; speedup 1.0000x reference)
//
#include <hip/hip_runtime.h>

typedef unsigned short u16;
typedef u16 u16x4 __attribute__((ext_vector_type(4)));
typedef u16 u16x8 __attribute__((ext_vector_type(8)));
typedef __bf16 bf16x8 __attribute__((ext_vector_type(8)));
typedef float f32x4 __attribute__((ext_vector_type(4)));
typedef unsigned u32x4 __attribute__((ext_vector_type(4)));

#define DEVI __device__ __forceinline__

#if __has_builtin(__builtin_amdgcn_exp2f)
#define EXP2F __builtin_amdgcn_exp2f
#else
#define EXP2F exp2f
#endif

// ---------- helpers ----------
DEVI u16 f2b(float f) {  // fp32 -> bf16 RNE
  unsigned u = __builtin_bit_cast(unsigned, f);
  u += 0x7fffu + ((u >> 16) & 1u);
  return (u16)(u >> 16);
}

DEVI float b2f(u16 v) { return __builtin_bit_cast(float, (unsigned)v << 16); }

DEVI unsigned cvtpk_bf16(float lo, float hi) {  // dword = {bf16(lo), bf16(hi)<<16}
  unsigned r;
  asm("v_cvt_pk_bf16_f32 %0, %1, %2" : "=v"(r) : "v"(lo), "v"(hi));
  return r;
}

DEVI f32x4 mfma16(u16x8 a, u16x8 b, f32x4 c) {
  return __builtin_amdgcn_mfma_f32_16x16x32_bf16(
      __builtin_bit_cast(bf16x8, a), __builtin_bit_cast(bf16x8, b), c, 0, 0, 0);
}

DEVI void async_copy16(const u16* g, u16* l) {
  __builtin_amdgcn_global_load_lds(
      (__attribute__((address_space(1))) unsigned int*)(g),
      (__attribute__((address_space(3))) unsigned int*)(l), 16, 0, 0);
}

// raw barrier with compiler memory fences on both sides (NOT __syncthreads:
// that emits s_waitcnt vmcnt(0) and would kill the counted-vmcnt pipeline)
DEVI void fence_barrier() {
  asm volatile("" ::: "memory");
  __builtin_amdgcn_s_barrier();
  asm volatile("" ::: "memory");
}

// XCD-aware bijective block swizzle (T1): dispatch round-robins XCDs, so
// logical = (flat%8)*(nwg/8) + flat/8 gives each XCD a CONTIGUOUS chunk of
// logical blocks -> data reuse stays within one XCD's L2. Requires nwg%8==0.
DEVI int xcd_swz(int flat, int nwg) {
  return (flat & 7) * (nwg >> 3) + (flat >> 3);
}

// ---------- 1. hs->bf16 + gate (float4 loads, u16x4 stores) ----------
__global__ void prep_kernel(const float* __restrict__ hs, const float* __restrict__ mask,
                            const float* __restrict__ ww, const float* __restrict__ wb,
                            u16* __restrict__ hsb, float* __restrict__ wgate) {
  int token = blockIdx.x;            // 0..4095
  int tid = threadIdx.x;             // 256
  const float4* row4 = (const float4*)(hs + (size_t)token * 1280);
  const float4* ww4 = (const float4*)ww;
  u16x4* orow4 = (u16x4*)(hsb + (size_t)token * 1280);
  float acc = 0.f;
#pragma unroll
  for (int i = 0; i < 2; i++) {
    int slot = i * 256 + tid;        // 320 float4 per row
    if (slot < 320) {
      float4 v = row4[slot];
      float4 w = ww4[slot];
      u16x4 o = {f2b(v.x), f2b(v.y), f2b(v.z), f2b(v.w)};
      orow4[slot] = o;
      acc += v.x * w.x + v.y * w.y + v.z * w.z + v.w * w.w;
    }
  }
#pragma unroll
  for (int off = 1; off < 64; off <<= 1) acc += __shfl_xor(acc, off);
  __shared__ float partial[4];
  int wid = tid >> 6;
  if ((tid & 63) == 0) partial[wid] = acc;
  __syncthreads();
  if (tid == 0) {
    float tot = partial[0] + partial[1] + partial[2] + partial[3];
    int b = token >> 11, t = token & 2047;
    int s = t & 1023;
    float mv = mask[b * 65536 + ((s >> 5) * 8) * 256 + (s & 31) * 8];
    float z = tot + mv * ww[1280] + wb[0];
    wgate[token] = 1.f / (1.f + __expf(-z));
  }
}

// ---------- 2. weight transpose + bf16 (float4 loads, u16x4 stores) ----------
__global__ void wtrans_kernel(const float* w0, const float* w1, const float* w2,
                              const float* w3, const float* w4, const float* w5,
                              const float* w6, float qscale, u16* __restrict__ out) {
  const float* src;
  switch (blockIdx.z) {
    case 0: src = w0; break; case 1: src = w1; break; case 2: src = w2; break;
    case 3: src = w3; break; case 4: src = w4; break; case 5: src = w5; break;
    default: src = w6; break;
  }
  float s = (blockIdx.z == 0 || blockIdx.z == 4) ? qscale : 1.f;
  u16* dst = out + (size_t)blockIdx.z * 1280 * 1280;
  __shared__ float tile[32][33];
  int k0 = blockIdx.x * 32, n0 = blockIdx.y * 32;
  // load: thread t -> src row k0+(t>>3), float4 at n0+(t&7)*4 (one pass = whole tile)
  {
    int lr = threadIdx.x >> 3, lc = threadIdx.x & 7;
    float4 v = *(const float4*)(src + (size_t)(k0 + lr) * 1280 + n0 + lc * 4);
    tile[lr][lc * 4 + 0] = v.x;
    tile[lr][lc * 4 + 1] = v.y;
    tile[lr][lc * 4 + 2] = v.z;
    tile[lr][lc * 4 + 3] = v.w;
  }
  __syncthreads();
  // store: thread t -> dst row n0+(t>>3), u16x4 at k0+(t&7)*4
  {
    int ty2 = threadIdx.x >> 3, tx2 = threadIdx.x & 7;
    u16x4 o = {f2b(tile[tx2 * 4 + 0][ty2] * s), f2b(tile[tx2 * 4 + 1][ty2] * s),
               f2b(tile[tx2 * 4 + 2][ty2] * s), f2b(tile[tx2 * 4 + 3][ty2] * s)};
    *(u16x4*)(dst + (size_t)(n0 + ty2) * 1280 + k0 + tx2 * 4) = o;
  }
}

// ---------- 3. merged QKV GEMM: one uniform 1280-block launch ----------
// R12 finding: qdual(640) + kv(640) as separate launches serialize on the
// stream at 62.5% slot occupancy each (2x fill/drain). Merged 1280-block
// launch streams continuously (~1 T_blk saved). R5's merged-kernel failure
// was the UNCAPPED allocator (172 VGPR -> 2 blk/CU); both paths have since
// proven <=128 under launch_bounds(256,4), and the wave-uniform z-branch
// means the per-path live sets don't overlap (union ~= max, fits the cap).
// z=0/1: 128x64 dual-weight Q blend (column half z) -> Qb
// z=2:   K (half-selected weights), 128x128 row-major -> Kb
// z=3:   V (half-selected), transposed -> VTb [b*8+h][160][2048]
// All z: 4 staging instr/thread, vmcnt(4) double-buffer, 16 MFMA/kk, 32KB LDS.
__launch_bounds__(256, 4)
__global__ void gemm_qkv_kernel(const u16* __restrict__ A, const u16* __restrict__ Wt,
                                const float* __restrict__ wgate,
                                u16* __restrict__ Qout, u16* __restrict__ Kout,
                                u16* __restrict__ VTout) {
  const int K = 1280, N = 1280;
  const size_t WSZ = (size_t)1280 * 1280;
  __shared__ u16 As[2][128 * 32];
  __shared__ u16 Bs[2][64 * 32];
  __shared__ u16 Bs2[2][64 * 32];

  int tid = threadIdx.x;
  int wid = tid >> 6, lane = tid & 63;
  int q = lane & 15, jl = lane >> 4;
  int flat = blockIdx.x + 10 * (blockIdx.y + 32 * blockIdx.z);
  flat = xcd_swz(flat, 1280);
  int nb = flat % 10;
  int rem = flat / 10;                      // 0..127
  int mb = rem & 31, z = rem >> 5;          // z: 0,1 = Q halves; 2 = K; 3 = V
  int m0 = mb * 128, n0 = nb * 128;
  bool dual = (z < 2);
  bool first = ((m0 & 2047) < 1024);        // first half of sequence -> attn weights

  const u16 *B0, *B1;
  if (dual)        { B0 = Wt + 0 * WSZ; B1 = Wt + 4 * WSZ; }
  else if (z == 2) { B0 = first ? Wt + 1 * WSZ : Wt + 5 * WSZ; B1 = B0; }
  else             { B0 = first ? Wt + 2 * WSZ : Wt + 6 * WSZ; B1 = B0; }

  f32x4 zero = {0.f, 0.f, 0.f, 0.f};
  f32x4 acc[4][4];
#pragma unroll
  for (int i = 0; i < 4; i++)
#pragma unroll
    for (int j = 0; j < 4; j++) acc[i][j] = zero;

  int wr = wid >> 1, wc = wid & 1;
  int brow = tid >> 2, bseg = tid & 3;      // B staging: 64 rows x 4 segs
  // dual: Bs/Bs2 = rows [n0+z*64, +64) of B0/B1
  // K/V:  Bs = rows [n0, +64) of B0, Bs2 = rows [n0+64, +128) of B0
  int nrow0 = dual ? (n0 + (z << 6) + brow) : (n0 + brow);
  const u16* Bp0 = B0 + (size_t)nrow0 * K;
  const u16* Bp1 = dual ? (B1 + (size_t)nrow0 * K) : (B0 + (size_t)(n0 + 64 + brow) * K);

#define QKVSTAGE(buf, kk)                                                         \
  do {                                                                            \
    int k0 = (kk) * 32;                                                           \
    _Pragma("unroll") for (int i = 0; i < 2; i++) {                               \
      int slot = i * 256 + tid;                                                   \
      int row = slot >> 2, seg = slot & 3;                                        \
      async_copy16(A + (size_t)(m0 + row) * K + k0 + seg * 8,                     \
                   As[buf] + (size_t)(i * 256 + wid * 64) * 8);                   \
    }                                                                             \
    async_copy16(Bp0 + k0 + bseg * 8, Bs[buf] + (size_t)tid * 8);                 \
    async_copy16(Bp1 + k0 + bseg * 8, Bs2[buf] + (size_t)tid * 8);                \
  } while (0)

  QKVSTAGE(0, 0);
  for (int kk = 0; kk < 40; kk++) {
    int cur = kk & 1;
    if (kk < 39) {
      QKVSTAGE(cur ^ 1, kk + 1);
      asm volatile("s_waitcnt vmcnt(4)" ::: "memory");
    } else {
      asm volatile("s_waitcnt vmcnt(0)" ::: "memory");
    }
    fence_barrier();

    u16x8 af[4];
#pragma unroll
    for (int mi = 0; mi < 4; mi++)
      af[mi] = *(const u16x8*)(As[cur] + (wr * 64 + mi * 16 + q) * 32 + jl * 8);
    if (dual) {
#pragma unroll
      for (int ni = 0; ni < 2; ni++) {
        u16x8 bf0 = *(const u16x8*)(Bs[cur] + (wc * 32 + ni * 16 + q) * 32 + jl * 8);
        u16x8 bf1 = *(const u16x8*)(Bs2[cur] + (wc * 32 + ni * 16 + q) * 32 + jl * 8);
#pragma unroll
        for (int mi = 0; mi < 4; mi++) {
          acc[mi][ni] = mfma16(af[mi], bf0, acc[mi][ni]);
          acc[mi][2 + ni] = mfma16(af[mi], bf1, acc[mi][2 + ni]);
        }
      }
    } else {
      const u16* Bsel = wc ? Bs2[cur] : Bs[cur];
      u16x8 bfr[4];
#pragma unroll
      for (int ni = 0; ni < 4; ni++)
        bfr[ni] = *(const u16x8*)(Bsel + (ni * 16 + q) * 32 + jl * 8);
#pragma unroll
      for (int mi = 0; mi < 4; mi++)
#pragma unroll
        for (int ni = 0; ni < 4; ni++)
          acc[mi][ni] = mfma16(af[mi], bfr[ni], acc[mi][ni]);
    }
    fence_barrier();
  }
#undef QKVSTAGE

  if (dual) {
    // blended Q epilogue (f32 blend; qscale pre-folded into weights)
#pragma unroll
    for (int mi = 0; mi < 4; mi++)
#pragma unroll
      for (int r = 0; r < 4; r++) {
        int row = m0 + wr * 64 + mi * 16 + (jl << 2) + r;
        float w = wgate[row];
#pragma unroll
        for (int ni = 0; ni < 2; ni++) {
          int col = n0 + (z << 6) + wc * 32 + ni * 16 + q;
          float v = w * acc[mi][ni][r] + (1.f - w) * acc[mi][2 + ni][r];
          Qout[(size_t)row * N + col] = f2b(v);
        }
      }
  } else if (z == 2) {
#pragma unroll
    for (int mi = 0; mi < 4; mi++)
#pragma unroll
      for (int ni = 0; ni < 4; ni++)
#pragma unroll
        for (int r = 0; r < 4; r++) {
          int row = m0 + wr * 64 + mi * 16 + (jl << 2) + r;
          int col = n0 + wc * 64 + ni * 16 + q;
          Kout[(size_t)row * N + col] = f2b(acc[mi][ni][r]);
        }
  } else {
    // V^T layout: [b*8+h][c_in (160)][s (2048)]
#pragma unroll
    for (int mi = 0; mi < 4; mi++)
#pragma unroll
      for (int ni = 0; ni < 4; ni++) {
        int row0 = m0 + wr * 64 + mi * 16 + (jl << 2);  // 4 consecutive tokens
        int col = n0 + wc * 64 + ni * 16 + q;
        int b = row0 >> 11, s = row0 & 2047;
        int h = col / 160, c_in = col - h * 160;
        u16x4 v = {f2b(acc[mi][ni][0]), f2b(acc[mi][ni][1]),
                   f2b(acc[mi][ni][2]), f2b(acc[mi][ni][3])};
        *(u16x4*)(VTout + ((size_t)(b * 8 + h) * 160 + c_in) * 2048 + s) = v;
      }
  }
}

// ---------- 4. flash attention: R7 structure (proven 86 us) + XCD swizzle ----------
// 512 threads = 8 waves x 16 q-rows sharing one K/V tile (LDS 40960 B).
// Port-bound optimum (R10 closed the q-doubling path: needs ~200 VGPR ->
// 8 waves/CU -> latency-exposed). XCD swizzle on blockIdx.x: FETCH 92->17 MB
// (R12, validated). Staging role-split: waves 0-3 K, 4-7 V (5 instr each);
// each wave drains only its OWN prefetch. Swapped MFMA, lane-scalar softmax,
// P transpose via cvt_pk + ds_bpermute. SPLIT=2: grid (256,2), NT=16.
template <int SPLIT>
__launch_bounds__(512)
__global__ void flash_kernel(const u16* __restrict__ Q, const u16* __restrict__ Kg,
                             const u16* __restrict__ VTg, u16* __restrict__ O,
                             u16* __restrict__ Opart, float* __restrict__ MLbuf) {
  const int C = 1280;
  int bid = xcd_swz(blockIdx.x, 256);
  int qb = bid & 15, h = (bid >> 4) & 7, b = bid >> 7;
  int sp = (SPLIT > 1) ? (int)blockIdx.y : 0;
  int tid = threadIdx.x, wid = tid >> 6, lane = tid & 63;
  int q = lane & 15, jl = lane >> 4;

  const int NT = 32 / SPLIT;
  const int t0 = sp * NT;

  const size_t baseQ = ((size_t)(b * 2048 + qb * 128)) * C + h * 160;
  const size_t baseK = ((size_t)(b * 2048)) * C + h * 160;
  const size_t baseVT = (size_t)(b * 8 + h) * 160 * 2048;

  __shared__ u16 Ks[64 * 160];     // 20480 B, chunk-swizzled
  __shared__ u16 Vts[160 * 64];    // 20480 B, chunk-swizzled  => total 40960 B

  // ---- role-split staging state (wave-uniform role by wid) ----
  const bool isK = (wid < 4);
  int sw = wid & 3;                 // stager index within role group
  const u16* sbase;
  u16* sdst;
  size_t sadv;
  unsigned soff[5];
  if (isK) {
    sbase = Kg + baseK + (size_t)(t0 * 64) * C;
    sdst = Ks;
    sadv = (size_t)64 * C;
#pragma unroll
    for (int j = 0; j < 5; j++) {
      int s = (sw + 4 * j) * 64 + lane;   // 16B-slot index, 0..1279
      int r = s / 20, cp = s - r * 20;
      int c = cp ^ ((r >> 1) & 3);        // inverse swizzle on global source
      soff[j] = (unsigned)(r * C + c * 8);
    }
  } else {
    sbase = VTg + baseVT + t0 * 64;
    sdst = Vts;
    sadv = 64;
#pragma unroll
    for (int j = 0; j < 5; j++) {
      int gc = (sw + 4 * j) * 64 + lane;
      int c = gc >> 3, jj = gc & 7;
      soff[j] = (unsigned)(c * 2048 + ((jj ^ (c & 7)) << 3));
    }
  }

#define STAGE5()                                                   \
  do {                                                             \
    _Pragma("unroll") for (int j = 0; j < 5; j++)                  \
        async_copy16(sbase + soff[j], sdst + (sw + 4 * j) * 512);  \
  } while (0)

  // per-lane constant K-read swizzle: chunk (ks*4+jl) stored at ^((q>>1)&3)
  const int kro = ((jl ^ ((q >> 1) & 3)) << 3);

  // P-transpose lane constants for ds_bpermute
  const int addr0 = (q + 16 * ((jl * 2 + 0) & 3)) << 2;
  const int addr1 = (q + 16 * ((jl * 2 + 1) & 3)) << 2;
  const bool hihalf = (lane >= 32);

  // Q fragments (issued first: oldest vmcnt entries)
  u16x8 qf[5];
  {
    const u16* qrow = Q + baseQ + (size_t)(wid * 16 + q) * C;
#pragma unroll
    for (int ks = 0; ks < 5; ks++)
      qf[ks] = *(const u16x8*)(qrow + ks * 32 + jl * 8);
  }

  f32x4 zero = {0.f, 0.f, 0.f, 0.f};
  f32x4 oacc[10];
#pragma unroll
  for (int i = 0; i < 10; i++) oacc[i] = zero;
  float mrow = -1e30f, lrow = 0.f;   // lane-scalar: this lane's q

  // prologue: each wave stages its own tile-0 role
  STAGE5();

  for (int kti = 0; kti < NT; kti++) {
    bool last = (kti == NT - 1);
    // K(t) ready: only K-stagers wait (their own 5 loads); V loads stay in flight
    if (isK) { asm volatile("s_waitcnt vmcnt(0)" ::: "memory"); }
    fence_barrier();

    // scores (swapped): sc[ct] col = q, row = kv = ct*16 + jl*4 + r
    f32x4 sc[4];
#pragma unroll
    for (int ct = 0; ct < 4; ct++) {
      f32x4 a = zero;
#pragma unroll
      for (int ks = 0; ks < 5; ks++) {
        u16x8 kf = *(const u16x8*)(&Ks[(ct * 16 + q) * 160 + ks * 32 + kro]);
        a = mfma16(kf, qf[ks], a);
      }
      sc[ct] = a;
    }

    fence_barrier();                    // all waves done reading Ks(t)
    if (isK && !last) { sbase += sadv; STAGE5(); }   // K(t+1) overlaps softmax+PV

    // ---- softmax, all state lane-scalar ----
    float m = sc[0][0];
#pragma unroll
    for (int ct = 0; ct < 4; ct++)
#pragma unroll
      for (int r = 0; r < 4; r++) m = fmaxf(m, sc[ct][r]);
    m = fmaxf(m, __shfl_xor(m, 16));
    m = fmaxf(m, __shfl_xor(m, 32));

    if (__any(m > mrow + 8.f)) {
      float mnew = fmaxf(mrow, m);
      float alpha = EXP2F(mrow - mnew);
      mrow = mnew;
      float rs = 0.f;
#pragma unroll
      for (int ct = 0; ct < 4; ct++)
#pragma unroll
        for (int r = 0; r < 4; r++) {
          float p = EXP2F(sc[ct][r] - mnew);
          sc[ct][r] = p;
          rs += p;
        }
      lrow = lrow * alpha + rs;
#pragma unroll
      for (int ci = 0; ci < 10; ci++) oacc[ci] *= alpha;
    } else {
      float rs = 0.f;
#pragma unroll
      for (int ct = 0; ct < 4; ct++)
#pragma unroll
        for (int r = 0; r < 4; r++) {
          float p = EXP2F(sc[ct][r] - mrow);
          sc[ct][r] = p;
          rs += p;
        }
      lrow += rs;
    }

    // pack P to bf16 pairs: pk0[ct] = {r0,r1}, pk1[ct] = {r2,r3}
    unsigned pk0[4], pk1[4];
#pragma unroll
    for (int ct = 0; ct < 4; ct++) {
      pk0[ct] = cvtpk_bf16(sc[ct][0], sc[ct][1]);
      pk1[ct] = cvtpk_bf16(sc[ct][2], sc[ct][3]);
    }

    // V(t) ready: only V-stagers wait (K(t+1) loads stay in flight)
    if (!isK) { asm volatile("s_waitcnt vmcnt(0)" ::: "memory"); }
    fence_barrier();

    // PV: pf built via ds_bpermute (register-only)
#pragma unroll
    for (int kt2 = 0; kt2 < 2; kt2++) {
      const int cA = kt2 * 2, cB = kt2 * 2 + 1;
      int a0 = __builtin_amdgcn_ds_bpermute(addr0, (int)pk0[cA]);
      int a1 = __builtin_amdgcn_ds_bpermute(addr0, (int)pk1[cA]);
      int a2 = __builtin_amdgcn_ds_bpermute(addr1, (int)pk0[cA]);
      int a3 = __builtin_amdgcn_ds_bpermute(addr1, (int)pk1[cA]);
      int b0 = __builtin_amdgcn_ds_bpermute(addr0, (int)pk0[cB]);
      int b1 = __builtin_amdgcn_ds_bpermute(addr0, (int)pk1[cB]);
      int b2 = __builtin_amdgcn_ds_bpermute(addr1, (int)pk0[cB]);
      int b3 = __builtin_amdgcn_ds_bpermute(addr1, (int)pk1[cB]);
      u32x4 d;
      d[0] = (unsigned)(hihalf ? b0 : a0);
      d[1] = (unsigned)(hihalf ? b1 : a1);
      d[2] = (unsigned)(hihalf ? b2 : a2);
      d[3] = (unsigned)(hihalf ? b3 : a3);
      u16x8 pf = __builtin_bit_cast(u16x8, d);
#pragma unroll
      for (int ci = 0; ci < 10; ci++) {
        int c = ci * 16 + q;
        int jj = kt2 * 4 + jl;
        u16x8 vf = *(const u16x8*)(&Vts[c * 64 + ((jj ^ (c & 7)) << 3)]);
        oacc[ci] = mfma16(vf, pf, oacc[ci]);   // col = q, row = c
      }
    }

    fence_barrier();                    // all waves done reading Vts(t)
    if (!isK && !last) { sbase += sadv; STAGE5(); }  // V(t+1) overlaps next QK
  }
#undef STAGE5

  // final l reduce across the 4 lane-groups
  lrow += __shfl_xor(lrow, 16);
  lrow += __shfl_xor(lrow, 32);
  float linv = 1.f / lrow;

  int qrow = qb * 128 + wid * 16 + q;
  if constexpr (SPLIT > 1) {
    size_t g0 = (size_t)sp * 4096 + (size_t)b * 2048 + qrow;
#pragma unroll
    for (int ci = 0; ci < 10; ci++) {
      int col = h * 160 + ci * 16 + (jl << 2);
      u16x4 v = {f2b(oacc[ci][0] * linv), f2b(oacc[ci][1] * linv),
                 f2b(oacc[ci][2] * linv), f2b(oacc[ci][3] * linv)};
      *(u16x4*)(Opart + g0 * 1280 + col) = v;
    }
    if (lane < 16) {
      size_t mi = (g0 * 8 + h) * 2;
      MLbuf[mi] = mrow;
      MLbuf[mi + 1] = lrow;
    }
  } else {
#pragma unroll
    for (int ci = 0; ci < 10; ci++) {
      int col = h * 160 + ci * 16 + (jl << 2);
      u16x4 v = {f2b(oacc[ci][0] * linv), f2b(oacc[ci][1] * linv),
                 f2b(oacc[ci][2] * linv), f2b(oacc[ci][3] * linv)};
      *(u16x4*)(O + ((size_t)(b * 2048) + qrow) * C + col) = v;
    }
  }
}

// ---------- 4b. combine the two kv-split parts (vec8) ----------
// O = (v0*a0*l0 + v1*a1*l1) / (a0*l0 + a1*l1), a_i = 2^(m_i - max m)
__global__ void combine_kernel(const u16* __restrict__ Opart, const float* __restrict__ MLbuf,
                               u16* __restrict__ O) {
  int idx = blockIdx.x * 256 + threadIdx.x;   // vec8 index, 655360 total
  int token = idx / 160;
  int h = (idx - token * 160) / 20;
  size_t i0 = ((size_t)token * 8 + h) * 2;
  const size_t MLP = (size_t)4096 * 16;       // floats per part
  float m0 = MLbuf[i0], l0 = MLbuf[i0 + 1];
  float m1 = MLbuf[i0 + MLP], l1 = MLbuf[i0 + MLP + 1];
  float m = fmaxf(m0, m1);
  float w0 = EXP2F(m0 - m) * l0, w1 = EXP2F(m1 - m) * l1;
  float inv = 1.f / (w0 + w1);
  w0 *= inv; w1 *= inv;
  const size_t OPP = (size_t)655360;          // vec8 per part
  u16x8 a = *(const u16x8*)(Opart + (size_t)idx * 8);
  u16x8 c = *(const u16x8*)(Opart + (OPP + idx) * 8);
  u16x8 o;
#pragma unroll
  for (int j = 0; j < 8; j++)
    o[j] = f2b(b2f(a[j]) * w0 + b2f(c[j]) * w1);
  *(u16x8*)(O + (size_t)idx * 8) = o;
}

// ---------- 5. out-proj GEMM, double-buffered: C = A@B0 + bias + resid ----------
__launch_bounds__(256, 4)
__global__ void gemm_out_kernel(const u16* __restrict__ A, const u16* __restrict__ Bt,
                                float* __restrict__ Cf, const float* __restrict__ bias,
                                const float* __restrict__ resid) {
  const int K = 1280, N = 1280;
  __shared__ u16 As[2][128 * 32];
  __shared__ u16 Bs[2][128 * 32];

  int tid = threadIdx.x;
  int wid = tid >> 6, lane = tid & 63;
  int flat = blockIdx.x + 10 * blockIdx.y;
  flat = xcd_swz(flat, 320);
  int nb = flat % 10, mb = flat / 10;
  int m0 = mb * 128, n0 = nb * 128;

  f32x4 zero = {0.f, 0.f, 0.f, 0.f};
  f32x4 acc[4][4];
#pragma unroll
  for (int i = 0; i < 4; i++)
#pragma unroll
    for (int j = 0; j < 4; j++) acc[i][j] = zero;

  int wr = wid >> 1, wc = wid & 1;

#define OSTAGE(buf, kk)                                                           \
  do {                                                                            \
    int k0 = (kk) * 32;                                                           \
    _Pragma("unroll") for (int i = 0; i < 2; i++) {                               \
      int slot = i * 256 + tid;                                                   \
      int row = slot >> 2, seg = slot & 3;                                        \
      async_copy16(A + (size_t)(m0 + row) * K + k0 + seg * 8,                     \
                   As[buf] + (size_t)(i * 256 + wid * 64) * 8);                   \
      async_copy16(Bt + (size_t)(n0 + row) * K + k0 + seg * 8,                    \
                   Bs[buf] + (size_t)(i * 256 + wid * 64) * 8);                   \
    }                                                                             \
  } while (0)

  OSTAGE(0, 0);
  for (int kk = 0; kk < 40; kk++) {
    int cur = kk & 1;
    if (kk < 39) {
      OSTAGE(cur ^ 1, kk + 1);
      asm volatile("s_waitcnt vmcnt(4)" ::: "memory");
    } else {
      asm volatile("s_waitcnt vmcnt(0)" ::: "memory");
    }
    fence_barrier();

    u16x8 af[4], bfr[4];
#pragma unroll
    for (int mi = 0; mi < 4; mi++)
      af[mi] = *(const u16x8*)(As[cur] + (wr * 64 + mi * 16 + (lane & 15)) * 32 + (lane >> 4) * 8);
#pragma unroll
    for (int ni = 0; ni < 4; ni++)
      bfr[ni] = *(const u16x8*)(Bs[cur] + (wc * 64 + ni * 16 + (lane & 15)) * 32 + (lane >> 4) * 8);
#pragma unroll
    for (int mi = 0; mi < 4; mi++)
#pragma unroll
      for (int ni = 0; ni < 4; ni++)
        acc[mi][ni] = mfma16(af[mi], bfr[ni], acc[mi][ni]);
    fence_barrier();
  }
#undef OSTAGE

#pragma unroll
  for (int mi = 0; mi < 4; mi++)
#pragma unroll
    for (int ni = 0; ni < 4; ni++)
#pragma unroll
      for (int r = 0; r < 4; r++) {
        int row = m0 + wr * 64 + mi * 16 + ((lane >> 4) << 2) + r;
        int col = n0 + wc * 64 + ni * 16 + (lane & 15);
        Cf[(size_t)row * N + col] = acc[mi][ni][r] + bias[col] + resid[(size_t)row * N + col];
      }
}

// ---------- launch ----------
extern "C" void kernel_launch(void* const* d_in, const int* in_sizes, int n_in,
                              void* d_out, int out_size, void* d_ws, size_t ws_size,
                              hipStream_t stream) {
  const float* hs      = (const float*)d_in[0];
  const float* mask    = (const float*)d_in[1];
  const float* attn_wq = (const float*)d_in[2];
  const float* attn_wk = (const float*)d_in[3];
  const float* attn_wv = (const float*)d_in[4];
  const float* out_w   = (const float*)d_in[5];
  const float* out_b   = (const float*)d_in[6];
  const float* proc_wq = (const float*)d_in[7];
  const float* proc_wk = (const float*)d_in[8];
  const float* proc_wv = (const float*)d_in[9];
  const float* ww      = (const float*)d_in[10];
  const float* wb      = (const float*)d_in[11];
  float* out = (float*)d_out;

  char* ws = (char*)d_ws;
  const size_t TOK = (size_t)4096 * 1280;     // tokens x channels
  u16* hsb = (u16*)(ws);
  u16* Qb  = (u16*)(ws + 2 * TOK);
  u16* Kb  = (u16*)(ws + 4 * TOK);
  u16* VTb = (u16*)(ws + 6 * TOK);            // V^T [16][160][2048]
  u16* AOb = (u16*)(ws + 8 * TOK);            // combine output / out-gemm input
  u16* Wt  = (u16*)(ws + 10 * TOK);           // 7 x 1280x1280 bf16
  float* wgate = (float*)(ws + 10 * TOK + (size_t)7 * 1280 * 1280 * 2);
  char* extra = ws + 10 * TOK + (size_t)7 * 1280 * 1280 * 2 + 16384;
  u16* Opart = (u16*)extra;                                     // [2][4096][1280] bf16
  float* MLbuf = (float*)(extra + (size_t)2 * 4096 * 1280 * 2); // [2][4096][8]{m,l}
  size_t need = (size_t)(extra - ws) + (size_t)2 * 4096 * 1280 * 2 + (size_t)2 * 4096 * 8 * 8;

  prep_kernel<<<4096, 256, 0, stream>>>(hs, mask, ww, wb, hsb, wgate);
  // 1/sqrt(160) * log2(e): scores land in log2 domain (folded into Q weights)
  const float qscale = 0.11405505533858971f;
  wtrans_kernel<<<dim3(40, 40, 7), 256, 0, stream>>>(attn_wq, attn_wk, attn_wv, out_w,
                                                     proc_wq, proc_wk, proc_wv, qscale, Wt);
  const size_t WSZ = (size_t)1280 * 1280;
  gemm_qkv_kernel<<<dim3(10, 32, 4), 256, 0, stream>>>(hsb, Wt, wgate, Qb, Kb, VTb);

  if (ws_size >= need) {
    flash_kernel<2><<<dim3(256, 2), 512, 0, stream>>>(Qb, Kb, VTb, nullptr, Opart, MLbuf);
    combine_kernel<<<2560, 256, 0, stream>>>(Opart, MLbuf, AOb);
  } else {
    flash_kernel<1><<<dim3(256, 1), 512, 0, stream>>>(Qb, Kb, VTb, AOb, nullptr, nullptr);
  }
  gemm_out_kernel<<<dim3(10, 32), 256, 0, stream>>>(AOb, Wt + 3 * WSZ, out, out_b, hs);
}

// Round 14
// 208.591 us; speedup vs baseline: 2.3646x; 2.3646x over previous
//
#include <hip/hip_runtime.h>

typedef unsigned short u16;
typedef u16 u16x4 __attribute__((ext_vector_type(4)));
typedef u16 u16x8 __attribute__((ext_vector_type(8)));
typedef __bf16 bf16x8 __attribute__((ext_vector_type(8)));
typedef float f32x4 __attribute__((ext_vector_type(4)));
typedef unsigned u32x4 __attribute__((ext_vector_type(4)));

#define DEVI __device__ __forceinline__

#if __has_builtin(__builtin_amdgcn_exp2f)
#define EXP2F __builtin_amdgcn_exp2f
#else
#define EXP2F exp2f
#endif

// ---------- helpers ----------
DEVI u16 f2b(float f) {  // fp32 -> bf16 RNE
  unsigned u = __builtin_bit_cast(unsigned, f);
  u += 0x7fffu + ((u >> 16) & 1u);
  return (u16)(u >> 16);
}

DEVI float b2f(u16 v) { return __builtin_bit_cast(float, (unsigned)v << 16); }

DEVI unsigned cvtpk_bf16(float lo, float hi) {  // dword = {bf16(lo), bf16(hi)<<16}
  unsigned r;
  asm("v_cvt_pk_bf16_f32 %0, %1, %2" : "=v"(r) : "v"(lo), "v"(hi));
  return r;
}

DEVI f32x4 mfma16(u16x8 a, u16x8 b, f32x4 c) {
  return __builtin_amdgcn_mfma_f32_16x16x32_bf16(
      __builtin_bit_cast(bf16x8, a), __builtin_bit_cast(bf16x8, b), c, 0, 0, 0);
}

DEVI void async_copy16(const u16* g, u16* l) {
  __builtin_amdgcn_global_load_lds(
      (__attribute__((address_space(1))) unsigned int*)(g),
      (__attribute__((address_space(3))) unsigned int*)(l), 16, 0, 0);
}

// raw barrier with compiler memory fences on both sides (NOT __syncthreads:
// that emits s_waitcnt vmcnt(0) and would kill the counted-vmcnt pipeline)
DEVI void fence_barrier() {
  asm volatile("" ::: "memory");
  __builtin_amdgcn_s_barrier();
  asm volatile("" ::: "memory");
}

// XCD-aware bijective block swizzle (T1): dispatch round-robins XCDs, so
// logical = (flat%8)*(nwg/8) + flat/8 gives each XCD a CONTIGUOUS chunk of
// logical blocks -> data reuse stays within one XCD's L2. Requires nwg%8==0.
DEVI int xcd_swz(int flat, int nwg) {
  return (flat & 7) * (nwg >> 3) + (flat >> 3);
}

// ---------- 1. hs->bf16 + gate (float4 loads, u16x4 stores) ----------
__global__ void prep_kernel(const float* __restrict__ hs, const float* __restrict__ mask,
                            const float* __restrict__ ww, const float* __restrict__ wb,
                            u16* __restrict__ hsb, float* __restrict__ wgate) {
  int token = blockIdx.x;            // 0..4095
  int tid = threadIdx.x;             // 256
  const float4* row4 = (const float4*)(hs + (size_t)token * 1280);
  const float4* ww4 = (const float4*)ww;
  u16x4* orow4 = (u16x4*)(hsb + (size_t)token * 1280);
  float acc = 0.f;
#pragma unroll
  for (int i = 0; i < 2; i++) {
    int slot = i * 256 + tid;        // 320 float4 per row
    if (slot < 320) {
      float4 v = row4[slot];
      float4 w = ww4[slot];
      u16x4 o = {f2b(v.x), f2b(v.y), f2b(v.z), f2b(v.w)};
      orow4[slot] = o;
      acc += v.x * w.x + v.y * w.y + v.z * w.z + v.w * w.w;
    }
  }
#pragma unroll
  for (int off = 1; off < 64; off <<= 1) acc += __shfl_xor(acc, off);
  __shared__ float partial[4];
  int wid = tid >> 6;
  if ((tid & 63) == 0) partial[wid] = acc;
  __syncthreads();
  if (tid == 0) {
    float tot = partial[0] + partial[1] + partial[2] + partial[3];
    int b = token >> 11, t = token & 2047;
    int s = t & 1023;
    float mv = mask[b * 65536 + ((s >> 5) * 8) * 256 + (s & 31) * 8];
    float z = tot + mv * ww[1280] + wb[0];
    wgate[token] = 1.f / (1.f + __expf(-z));
  }
}

// ---------- 2. weight transpose + bf16 (float4 loads, u16x4 stores) ----------
__global__ void wtrans_kernel(const float* w0, const float* w1, const float* w2,
                              const float* w3, const float* w4, const float* w5,
                              const float* w6, float qscale, u16* __restrict__ out) {
  const float* src;
  switch (blockIdx.z) {
    case 0: src = w0; break; case 1: src = w1; break; case 2: src = w2; break;
    case 3: src = w3; break; case 4: src = w4; break; case 5: src = w5; break;
    default: src = w6; break;
  }
  float s = (blockIdx.z == 0 || blockIdx.z == 4) ? qscale : 1.f;
  u16* dst = out + (size_t)blockIdx.z * 1280 * 1280;
  __shared__ float tile[32][33];
  int k0 = blockIdx.x * 32, n0 = blockIdx.y * 32;
  // load: thread t -> src row k0+(t>>3), float4 at n0+(t&7)*4 (one pass = whole tile)
  {
    int lr = threadIdx.x >> 3, lc = threadIdx.x & 7;
    float4 v = *(const float4*)(src + (size_t)(k0 + lr) * 1280 + n0 + lc * 4);
    tile[lr][lc * 4 + 0] = v.x;
    tile[lr][lc * 4 + 1] = v.y;
    tile[lr][lc * 4 + 2] = v.z;
    tile[lr][lc * 4 + 3] = v.w;
  }
  __syncthreads();
  // store: thread t -> dst row n0+(t>>3), u16x4 at k0+(t&7)*4
  {
    int ty2 = threadIdx.x >> 3, tx2 = threadIdx.x & 7;
    u16x4 o = {f2b(tile[tx2 * 4 + 0][ty2] * s), f2b(tile[tx2 * 4 + 1][ty2] * s),
               f2b(tile[tx2 * 4 + 2][ty2] * s), f2b(tile[tx2 * 4 + 3][ty2] * s)};
    *(u16x4*)(dst + (size_t)(n0 + ty2) * 1280 + k0 + tx2 * 4) = o;
  }
}

// ---------- 3a. dual-weight Q GEMM, double-buffered (counted vmcnt) ----------
// 128x64 tile of BOTH A@attn_wq and A@proc_wq; f32 blend w/ wgate -> Qb.
// LDS 2x16KB = 32KB -> 4 blocks/CU; prefetch next kk, wait vmcnt(4).
// XCD swizzle (nwg=640) keeps A-tile reuse within one XCD's L2.
// [R13 lesson: do NOT merge with gemm_kv — the multi-path union makes the
// allocator pick a 64-VGPR budget and spill everything (WRITE 904 MB).]
__launch_bounds__(256, 4)
__global__ void gemm_qdual_kernel(const u16* __restrict__ A, const u16* __restrict__ Wt,
                                  const float* __restrict__ wgate,
                                  u16* __restrict__ Qout) {
  const int K = 1280, N = 1280;
  const size_t WSZ = (size_t)1280 * 1280;
  __shared__ u16 As[2][128 * 32];
  __shared__ u16 Bs[2][64 * 32];
  __shared__ u16 Bs2[2][64 * 32];

  int tid = threadIdx.x;
  int wid = tid >> 6, lane = tid & 63;
  int q = lane & 15, jl = lane >> 4;
  int flat = blockIdx.x + 10 * (blockIdx.y + 32 * blockIdx.z);
  flat = xcd_swz(flat, 640);
  int nb = flat % 10;
  int rem = flat / 10;
  int mb = rem & 31, z = rem >> 5;          // z: column half
  int m0 = mb * 128, n0 = nb * 128;

  const u16* B0 = Wt + 0 * WSZ;
  const u16* B1 = Wt + 4 * WSZ;

  f32x4 zero = {0.f, 0.f, 0.f, 0.f};
  f32x4 acc[4][4];
#pragma unroll
  for (int i = 0; i < 4; i++)
#pragma unroll
    for (int j = 0; j < 4; j++) acc[i][j] = zero;

  int wr = wid >> 1, wc = wid & 1;
  int brow = tid >> 2, bseg = tid & 3;      // B staging: 64 rows x 4 segs
  int nrow = n0 + (z << 6) + brow;

#define QSTAGE(buf, kk)                                                           \
  do {                                                                            \
    int k0 = (kk) * 32;                                                           \
    _Pragma("unroll") for (int i = 0; i < 2; i++) {                               \
      int slot = i * 256 + tid;                                                   \
      int row = slot >> 2, seg = slot & 3;                                        \
      async_copy16(A + (size_t)(m0 + row) * K + k0 + seg * 8,                     \
                   As[buf] + (size_t)(i * 256 + wid * 64) * 8);                   \
    }                                                                             \
    async_copy16(B0 + (size_t)nrow * K + k0 + bseg * 8, Bs[buf] + (size_t)tid * 8);   \
    async_copy16(B1 + (size_t)nrow * K + k0 + bseg * 8, Bs2[buf] + (size_t)tid * 8);  \
  } while (0)

  QSTAGE(0, 0);
  for (int kk = 0; kk < 40; kk++) {
    int cur = kk & 1;
    if (kk < 39) {
      QSTAGE(cur ^ 1, kk + 1);
      asm volatile("s_waitcnt vmcnt(4)" ::: "memory");
    } else {
      asm volatile("s_waitcnt vmcnt(0)" ::: "memory");
    }
    fence_barrier();

    u16x8 af[4];
#pragma unroll
    for (int mi = 0; mi < 4; mi++)
      af[mi] = *(const u16x8*)(As[cur] + (wr * 64 + mi * 16 + q) * 32 + jl * 8);
#pragma unroll
    for (int ni = 0; ni < 2; ni++) {
      u16x8 bf0 = *(const u16x8*)(Bs[cur] + (wc * 32 + ni * 16 + q) * 32 + jl * 8);
      u16x8 bf1 = *(const u16x8*)(Bs2[cur] + (wc * 32 + ni * 16 + q) * 32 + jl * 8);
#pragma unroll
      for (int mi = 0; mi < 4; mi++) {
        acc[mi][ni] = mfma16(af[mi], bf0, acc[mi][ni]);
        acc[mi][2 + ni] = mfma16(af[mi], bf1, acc[mi][2 + ni]);
      }
    }
    fence_barrier();
  }
#undef QSTAGE

  // blended Q epilogue (f32 blend; qscale pre-folded into weights)
#pragma unroll
  for (int mi = 0; mi < 4; mi++)
#pragma unroll
    for (int r = 0; r < 4; r++) {
      int row = m0 + wr * 64 + mi * 16 + (jl << 2) + r;
      float w = wgate[row];
#pragma unroll
      for (int ni = 0; ni < 2; ni++) {
        int col = n0 + (z << 6) + wc * 32 + ni * 16 + q;
        float v = w * acc[mi][ni][r] + (1.f - w) * acc[mi][2 + ni][r];
        Qout[(size_t)row * N + col] = f2b(v);
      }
    }
}

// ---------- 3b. K/V GEMM (half-selected weights), double-buffered ----------
// z=0: K row-major -> Kb ; z=1: V -> VTb transposed [b*8+h][160][2048]
__launch_bounds__(256, 4)
__global__ void gemm_kv_kernel(const u16* __restrict__ A, const u16* __restrict__ Wt,
                               u16* __restrict__ Kout, u16* __restrict__ VTout) {
  const int K = 1280, N = 1280;
  const size_t WSZ = (size_t)1280 * 1280;
  __shared__ u16 As[2][128 * 32];
  __shared__ u16 Bs[2][64 * 32];
  __shared__ u16 Bs2[2][64 * 32];

  int tid = threadIdx.x;
  int wid = tid >> 6, lane = tid & 63;
  int q = lane & 15, jl = lane >> 4;
  int flat = blockIdx.x + 10 * (blockIdx.y + 32 * blockIdx.z);
  flat = xcd_swz(flat, 640);
  int nb = flat % 10;
  int rem = flat / 10;
  int mb = rem & 31;
  bool isV = (rem >> 5) == 1;
  int m0 = mb * 128, n0 = nb * 128;
  bool first = ((m0 & 2047) < 1024);   // first half of sequence -> attn weights

  const u16* B0 = isV ? (first ? Wt + 2 * WSZ : Wt + 6 * WSZ)
                      : (first ? Wt + 1 * WSZ : Wt + 5 * WSZ);

  f32x4 zero = {0.f, 0.f, 0.f, 0.f};
  f32x4 acc[4][4];
#pragma unroll
  for (int i = 0; i < 4; i++)
#pragma unroll
    for (int j = 0; j < 4; j++) acc[i][j] = zero;

  int wr = wid >> 1, wc = wid & 1;
  int brow = tid >> 2, bseg = tid & 3;

#define KVSTAGE(buf, kk)                                                          \
  do {                                                                            \
    int k0 = (kk) * 32;                                                           \
    _Pragma("unroll") for (int i = 0; i < 2; i++) {                               \
      int slot = i * 256 + tid;                                                   \
      int row = slot >> 2, seg = slot & 3;                                        \
      async_copy16(A + (size_t)(m0 + row) * K + k0 + seg * 8,                     \
                   As[buf] + (size_t)(i * 256 + wid * 64) * 8);                   \
    }                                                                             \
    async_copy16(B0 + (size_t)(n0 + brow) * K + k0 + bseg * 8, Bs[buf] + (size_t)tid * 8);       \
    async_copy16(B0 + (size_t)(n0 + 64 + brow) * K + k0 + bseg * 8, Bs2[buf] + (size_t)tid * 8); \
  } while (0)

  KVSTAGE(0, 0);
  for (int kk = 0; kk < 40; kk++) {
    int cur = kk & 1;
    if (kk < 39) {
      KVSTAGE(cur ^ 1, kk + 1);
      asm volatile("s_waitcnt vmcnt(4)" ::: "memory");
    } else {
      asm volatile("s_waitcnt vmcnt(0)" ::: "memory");
    }
    fence_barrier();

    u16x8 af[4];
#pragma unroll
    for (int mi = 0; mi < 4; mi++)
      af[mi] = *(const u16x8*)(As[cur] + (wr * 64 + mi * 16 + q) * 32 + jl * 8);
    const u16* Bsel = wc ? Bs2[cur] : Bs[cur];
    u16x8 bfr[4];
#pragma unroll
    for (int ni = 0; ni < 4; ni++)
      bfr[ni] = *(const u16x8*)(Bsel + (ni * 16 + q) * 32 + jl * 8);
#pragma unroll
    for (int mi = 0; mi < 4; mi++)
#pragma unroll
      for (int ni = 0; ni < 4; ni++)
        acc[mi][ni] = mfma16(af[mi], bfr[ni], acc[mi][ni]);
    fence_barrier();
  }
#undef KVSTAGE

  if (!isV) {
#pragma unroll
    for (int mi = 0; mi < 4; mi++)
#pragma unroll
      for (int ni = 0; ni < 4; ni++)
#pragma unroll
        for (int r = 0; r < 4; r++) {
          int row = m0 + wr * 64 + mi * 16 + (jl << 2) + r;
          int col = n0 + wc * 64 + ni * 16 + q;
          Kout[(size_t)row * N + col] = f2b(acc[mi][ni][r]);
        }
  } else {
    // V^T layout: [b*8+h][c_in (160)][s (2048)]
#pragma unroll
    for (int mi = 0; mi < 4; mi++)
#pragma unroll
      for (int ni = 0; ni < 4; ni++) {
        int row0 = m0 + wr * 64 + mi * 16 + (jl << 2);  // 4 consecutive tokens
        int col = n0 + wc * 64 + ni * 16 + q;
        int b = row0 >> 11, s = row0 & 2047;
        int h = col / 160, c_in = col - h * 160;
        u16x4 v = {f2b(acc[mi][ni][0]), f2b(acc[mi][ni][1]),
                   f2b(acc[mi][ni][2]), f2b(acc[mi][ni][3])};
        *(u16x4*)(VTout + ((size_t)(b * 8 + h) * 160 + c_in) * 2048 + s) = v;
      }
  }
}

// ---------- 4. flash attention: R7 structure (proven 86 us) + XCD swizzle ----------
// 512 threads = 8 waves x 16 q-rows sharing one K/V tile (LDS 40960 B).
// Port-bound optimum (R10 closed the q-doubling path: needs ~200 VGPR ->
// 8 waves/CU -> latency-exposed). XCD swizzle on blockIdx.x: FETCH 92->17 MB
// (R12, validated). Staging role-split: waves 0-3 K, 4-7 V (5 instr each);
// each wave drains only its OWN prefetch. Swapped MFMA, lane-scalar softmax,
// P transpose via cvt_pk + ds_bpermute. SPLIT=2: grid (256,2), NT=16.
template <int SPLIT>
__launch_bounds__(512)
__global__ void flash_kernel(const u16* __restrict__ Q, const u16* __restrict__ Kg,
                             const u16* __restrict__ VTg, u16* __restrict__ O,
                             u16* __restrict__ Opart, float* __restrict__ MLbuf) {
  const int C = 1280;
  int bid = xcd_swz(blockIdx.x, 256);
  int qb = bid & 15, h = (bid >> 4) & 7, b = bid >> 7;
  int sp = (SPLIT > 1) ? (int)blockIdx.y : 0;
  int tid = threadIdx.x, wid = tid >> 6, lane = tid & 63;
  int q = lane & 15, jl = lane >> 4;

  const int NT = 32 / SPLIT;
  const int t0 = sp * NT;

  const size_t baseQ = ((size_t)(b * 2048 + qb * 128)) * C + h * 160;
  const size_t baseK = ((size_t)(b * 2048)) * C + h * 160;
  const size_t baseVT = (size_t)(b * 8 + h) * 160 * 2048;

  __shared__ u16 Ks[64 * 160];     // 20480 B, chunk-swizzled
  __shared__ u16 Vts[160 * 64];    // 20480 B, chunk-swizzled  => total 40960 B

  // ---- role-split staging state (wave-uniform role by wid) ----
  const bool isK = (wid < 4);
  int sw = wid & 3;                 // stager index within role group
  const u16* sbase;
  u16* sdst;
  size_t sadv;
  unsigned soff[5];
  if (isK) {
    sbase = Kg + baseK + (size_t)(t0 * 64) * C;
    sdst = Ks;
    sadv = (size_t)64 * C;
#pragma unroll
    for (int j = 0; j < 5; j++) {
      int s = (sw + 4 * j) * 64 + lane;   // 16B-slot index, 0..1279
      int r = s / 20, cp = s - r * 20;
      int c = cp ^ ((r >> 1) & 3);        // inverse swizzle on global source
      soff[j] = (unsigned)(r * C + c * 8);
    }
  } else {
    sbase = VTg + baseVT + t0 * 64;
    sdst = Vts;
    sadv = 64;
#pragma unroll
    for (int j = 0; j < 5; j++) {
      int gc = (sw + 4 * j) * 64 + lane;
      int c = gc >> 3, jj = gc & 7;
      soff[j] = (unsigned)(c * 2048 + ((jj ^ (c & 7)) << 3));
    }
  }

#define STAGE5()                                                   \
  do {                                                             \
    _Pragma("unroll") for (int j = 0; j < 5; j++)                  \
        async_copy16(sbase + soff[j], sdst + (sw + 4 * j) * 512);  \
  } while (0)

  // per-lane constant K-read swizzle: chunk (ks*4+jl) stored at ^((q>>1)&3)
  const int kro = ((jl ^ ((q >> 1) & 3)) << 3);

  // P-transpose lane constants for ds_bpermute
  const int addr0 = (q + 16 * ((jl * 2 + 0) & 3)) << 2;
  const int addr1 = (q + 16 * ((jl * 2 + 1) & 3)) << 2;
  const bool hihalf = (lane >= 32);

  // Q fragments (issued first: oldest vmcnt entries)
  u16x8 qf[5];
  {
    const u16* qrow = Q + baseQ + (size_t)(wid * 16 + q) * C;
#pragma unroll
    for (int ks = 0; ks < 5; ks++)
      qf[ks] = *(const u16x8*)(qrow + ks * 32 + jl * 8);
  }

  f32x4 zero = {0.f, 0.f, 0.f, 0.f};
  f32x4 oacc[10];
#pragma unroll
  for (int i = 0; i < 10; i++) oacc[i] = zero;
  float mrow = -1e30f, lrow = 0.f;   // lane-scalar: this lane's q

  // prologue: each wave stages its own tile-0 role
  STAGE5();

  for (int kti = 0; kti < NT; kti++) {
    bool last = (kti == NT - 1);
    // K(t) ready: only K-stagers wait (their own 5 loads); V loads stay in flight
    if (isK) { asm volatile("s_waitcnt vmcnt(0)" ::: "memory"); }
    fence_barrier();

    // scores (swapped): sc[ct] col = q, row = kv = ct*16 + jl*4 + r
    f32x4 sc[4];
#pragma unroll
    for (int ct = 0; ct < 4; ct++) {
      f32x4 a = zero;
#pragma unroll
      for (int ks = 0; ks < 5; ks++) {
        u16x8 kf = *(const u16x8*)(&Ks[(ct * 16 + q) * 160 + ks * 32 + kro]);
        a = mfma16(kf, qf[ks], a);
      }
      sc[ct] = a;
    }

    fence_barrier();                    // all waves done reading Ks(t)
    if (isK && !last) { sbase += sadv; STAGE5(); }   // K(t+1) overlaps softmax+PV

    // ---- softmax, all state lane-scalar ----
    float m = sc[0][0];
#pragma unroll
    for (int ct = 0; ct < 4; ct++)
#pragma unroll
      for (int r = 0; r < 4; r++) m = fmaxf(m, sc[ct][r]);
    m = fmaxf(m, __shfl_xor(m, 16));
    m = fmaxf(m, __shfl_xor(m, 32));

    if (__any(m > mrow + 8.f)) {
      float mnew = fmaxf(mrow, m);
      float alpha = EXP2F(mrow - mnew);
      mrow = mnew;
      float rs = 0.f;
#pragma unroll
      for (int ct = 0; ct < 4; ct++)
#pragma unroll
        for (int r = 0; r < 4; r++) {
          float p = EXP2F(sc[ct][r] - mnew);
          sc[ct][r] = p;
          rs += p;
        }
      lrow = lrow * alpha + rs;
#pragma unroll
      for (int ci = 0; ci < 10; ci++) oacc[ci] *= alpha;
    } else {
      float rs = 0.f;
#pragma unroll
      for (int ct = 0; ct < 4; ct++)
#pragma unroll
        for (int r = 0; r < 4; r++) {
          float p = EXP2F(sc[ct][r] - mrow);
          sc[ct][r] = p;
          rs += p;
        }
      lrow += rs;
    }

    // pack P to bf16 pairs: pk0[ct] = {r0,r1}, pk1[ct] = {r2,r3}
    unsigned pk0[4], pk1[4];
#pragma unroll
    for (int ct = 0; ct < 4; ct++) {
      pk0[ct] = cvtpk_bf16(sc[ct][0], sc[ct][1]);
      pk1[ct] = cvtpk_bf16(sc[ct][2], sc[ct][3]);
    }

    // V(t) ready: only V-stagers wait (K(t+1) loads stay in flight)
    if (!isK) { asm volatile("s_waitcnt vmcnt(0)" ::: "memory"); }
    fence_barrier();

    // PV: pf built via ds_bpermute (register-only)
#pragma unroll
    for (int kt2 = 0; kt2 < 2; kt2++) {
      const int cA = kt2 * 2, cB = kt2 * 2 + 1;
      int a0 = __builtin_amdgcn_ds_bpermute(addr0, (int)pk0[cA]);
      int a1 = __builtin_amdgcn_ds_bpermute(addr0, (int)pk1[cA]);
      int a2 = __builtin_amdgcn_ds_bpermute(addr1, (int)pk0[cA]);
      int a3 = __builtin_amdgcn_ds_bpermute(addr1, (int)pk1[cA]);
      int b0 = __builtin_amdgcn_ds_bpermute(addr0, (int)pk0[cB]);
      int b1 = __builtin_amdgcn_ds_bpermute(addr0, (int)pk1[cB]);
      int b2 = __builtin_amdgcn_ds_bpermute(addr1, (int)pk0[cB]);
      int b3 = __builtin_amdgcn_ds_bpermute(addr1, (int)pk1[cB]);
      u32x4 d;
      d[0] = (unsigned)(hihalf ? b0 : a0);
      d[1] = (unsigned)(hihalf ? b1 : a1);
      d[2] = (unsigned)(hihalf ? b2 : a2);
      d[3] = (unsigned)(hihalf ? b3 : a3);
      u16x8 pf = __builtin_bit_cast(u16x8, d);
#pragma unroll
      for (int ci = 0; ci < 10; ci++) {
        int c = ci * 16 + q;
        int jj = kt2 * 4 + jl;
        u16x8 vf = *(const u16x8*)(&Vts[c * 64 + ((jj ^ (c & 7)) << 3)]);
        oacc[ci] = mfma16(vf, pf, oacc[ci]);   // col = q, row = c
      }
    }

    fence_barrier();                    // all waves done reading Vts(t)
    if (!isK && !last) { sbase += sadv; STAGE5(); }  // V(t+1) overlaps next QK
  }
#undef STAGE5

  // final l reduce across the 4 lane-groups
  lrow += __shfl_xor(lrow, 16);
  lrow += __shfl_xor(lrow, 32);
  float linv = 1.f / lrow;

  int qrow = qb * 128 + wid * 16 + q;
  if constexpr (SPLIT > 1) {
    size_t g0 = (size_t)sp * 4096 + (size_t)b * 2048 + qrow;
#pragma unroll
    for (int ci = 0; ci < 10; ci++) {
      int col = h * 160 + ci * 16 + (jl << 2);
      u16x4 v = {f2b(oacc[ci][0] * linv), f2b(oacc[ci][1] * linv),
                 f2b(oacc[ci][2] * linv), f2b(oacc[ci][3] * linv)};
      *(u16x4*)(Opart + g0 * 1280 + col) = v;
    }
    if (lane < 16) {
      size_t mi = (g0 * 8 + h) * 2;
      MLbuf[mi] = mrow;
      MLbuf[mi + 1] = lrow;
    }
  } else {
#pragma unroll
    for (int ci = 0; ci < 10; ci++) {
      int col = h * 160 + ci * 16 + (jl << 2);
      u16x4 v = {f2b(oacc[ci][0] * linv), f2b(oacc[ci][1] * linv),
                 f2b(oacc[ci][2] * linv), f2b(oacc[ci][3] * linv)};
      *(u16x4*)(O + ((size_t)(b * 2048) + qrow) * C + col) = v;
    }
  }
}

// ---------- 4b. combine the two kv-split parts (vec8) ----------
// O = (v0*a0*l0 + v1*a1*l1) / (a0*l0 + a1*l1), a_i = 2^(m_i - max m)
__global__ void combine_kernel(const u16* __restrict__ Opart, const float* __restrict__ MLbuf,
                               u16* __restrict__ O) {
  int idx = blockIdx.x * 256 + threadIdx.x;   // vec8 index, 655360 total
  int token = idx / 160;
  int h = (idx - token * 160) / 20;
  size_t i0 = ((size_t)token * 8 + h) * 2;
  const size_t MLP = (size_t)4096 * 16;       // floats per part
  float m0 = MLbuf[i0], l0 = MLbuf[i0 + 1];
  float m1 = MLbuf[i0 + MLP], l1 = MLbuf[i0 + MLP + 1];
  float m = fmaxf(m0, m1);
  float w0 = EXP2F(m0 - m) * l0, w1 = EXP2F(m1 - m) * l1;
  float inv = 1.f / (w0 + w1);
  w0 *= inv; w1 *= inv;
  const size_t OPP = (size_t)655360;          // vec8 per part
  u16x8 a = *(const u16x8*)(Opart + (size_t)idx * 8);
  u16x8 c = *(const u16x8*)(Opart + (OPP + idx) * 8);
  u16x8 o;
#pragma unroll
  for (int j = 0; j < 8; j++)
    o[j] = f2b(b2f(a[j]) * w0 + b2f(c[j]) * w1);
  *(u16x8*)(O + (size_t)idx * 8) = o;
}

// ---------- 5. out-proj GEMM, double-buffered: C = A@B0 + bias + resid ----------
__launch_bounds__(256, 4)
__global__ void gemm_out_kernel(const u16* __restrict__ A, const u16* __restrict__ Bt,
                                float* __restrict__ Cf, const float* __restrict__ bias,
                                const float* __restrict__ resid) {
  const int K = 1280, N = 1280;
  __shared__ u16 As[2][128 * 32];
  __shared__ u16 Bs[2][128 * 32];

  int tid = threadIdx.x;
  int wid = tid >> 6, lane = tid & 63;
  int flat = blockIdx.x + 10 * blockIdx.y;
  flat = xcd_swz(flat, 320);
  int nb = flat % 10, mb = flat / 10;
  int m0 = mb * 128, n0 = nb * 128;

  f32x4 zero = {0.f, 0.f, 0.f, 0.f};
  f32x4 acc[4][4];
#pragma unroll
  for (int i = 0; i < 4; i++)
#pragma unroll
    for (int j = 0; j < 4; j++) acc[i][j] = zero;

  int wr = wid >> 1, wc = wid & 1;

#define OSTAGE(buf, kk)                                                           \
  do {                                                                            \
    int k0 = (kk) * 32;                                                           \
    _Pragma("unroll") for (int i = 0; i < 2; i++) {                               \
      int slot = i * 256 + tid;                                                   \
      int row = slot >> 2, seg = slot & 3;                                        \
      async_copy16(A + (size_t)(m0 + row) * K + k0 + seg * 8,                     \
                   As[buf] + (size_t)(i * 256 + wid * 64) * 8);                   \
      async_copy16(Bt + (size_t)(n0 + row) * K + k0 + seg * 8,                    \
                   Bs[buf] + (size_t)(i * 256 + wid * 64) * 8);                   \
    }                                                                             \
  } while (0)

  OSTAGE(0, 0);
  for (int kk = 0; kk < 40; kk++) {
    int cur = kk & 1;
    if (kk < 39) {
      OSTAGE(cur ^ 1, kk + 1);
      asm volatile("s_waitcnt vmcnt(4)" ::: "memory");
    } else {
      asm volatile("s_waitcnt vmcnt(0)" ::: "memory");
    }
    fence_barrier();

    u16x8 af[4], bfr[4];
#pragma unroll
    for (int mi = 0; mi < 4; mi++)
      af[mi] = *(const u16x8*)(As[cur] + (wr * 64 + mi * 16 + (lane & 15)) * 32 + (lane >> 4) * 8);
#pragma unroll
    for (int ni = 0; ni < 4; ni++)
      bfr[ni] = *(const u16x8*)(Bs[cur] + (wc * 64 + ni * 16 + (lane & 15)) * 32 + (lane >> 4) * 8);
#pragma unroll
    for (int mi = 0; mi < 4; mi++)
#pragma unroll
      for (int ni = 0; ni < 4; ni++)
        acc[mi][ni] = mfma16(af[mi], bfr[ni], acc[mi][ni]);
    fence_barrier();
  }
#undef OSTAGE

#pragma unroll
  for (int mi = 0; mi < 4; mi++)
#pragma unroll
    for (int ni = 0; ni < 4; ni++)
#pragma unroll
      for (int r = 0; r < 4; r++) {
        int row = m0 + wr * 64 + mi * 16 + ((lane >> 4) << 2) + r;
        int col = n0 + wc * 64 + ni * 16 + (lane & 15);
        Cf[(size_t)row * N + col] = acc[mi][ni][r] + bias[col] + resid[(size_t)row * N + col];
      }
}

// ---------- launch ----------
extern "C" void kernel_launch(void* const* d_in, const int* in_sizes, int n_in,
                              void* d_out, int out_size, void* d_ws, size_t ws_size,
                              hipStream_t stream) {
  const float* hs      = (const float*)d_in[0];
  const float* mask    = (const float*)d_in[1];
  const float* attn_wq = (const float*)d_in[2];
  const float* attn_wk = (const float*)d_in[3];
  const float* attn_wv = (const float*)d_in[4];
  const float* out_w   = (const float*)d_in[5];
  const float* out_b   = (const float*)d_in[6];
  const float* proc_wq = (const float*)d_in[7];
  const float* proc_wk = (const float*)d_in[8];
  const float* proc_wv = (const float*)d_in[9];
  const float* ww      = (const float*)d_in[10];
  const float* wb      = (const float*)d_in[11];
  float* out = (float*)d_out;

  char* ws = (char*)d_ws;
  const size_t TOK = (size_t)4096 * 1280;     // tokens x channels
  u16* hsb = (u16*)(ws);
  u16* Qb  = (u16*)(ws + 2 * TOK);
  u16* Kb  = (u16*)(ws + 4 * TOK);
  u16* VTb = (u16*)(ws + 6 * TOK);            // V^T [16][160][2048]
  u16* AOb = (u16*)(ws + 8 * TOK);            // combine output / out-gemm input
  u16* Wt  = (u16*)(ws + 10 * TOK);           // 7 x 1280x1280 bf16
  float* wgate = (float*)(ws + 10 * TOK + (size_t)7 * 1280 * 1280 * 2);
  char* extra = ws + 10 * TOK + (size_t)7 * 1280 * 1280 * 2 + 16384;
  u16* Opart = (u16*)extra;                                     // [2][4096][1280] bf16
  float* MLbuf = (float*)(extra + (size_t)2 * 4096 * 1280 * 2); // [2][4096][8]{m,l}
  size_t need = (size_t)(extra - ws) + (size_t)2 * 4096 * 1280 * 2 + (size_t)2 * 4096 * 8 * 8;

  prep_kernel<<<4096, 256, 0, stream>>>(hs, mask, ww, wb, hsb, wgate);
  // 1/sqrt(160) * log2(e): scores land in log2 domain (folded into Q weights)
  const float qscale = 0.11405505533858971f;
  wtrans_kernel<<<dim3(40, 40, 7), 256, 0, stream>>>(attn_wq, attn_wk, attn_wv, out_w,
                                                     proc_wq, proc_wk, proc_wv, qscale, Wt);
  const size_t WSZ = (size_t)1280 * 1280;
  gemm_qdual_kernel<<<dim3(10, 32, 2), 256, 0, stream>>>(hsb, Wt, wgate, Qb);
  gemm_kv_kernel<<<dim3(10, 32, 2), 256, 0, stream>>>(hsb, Wt, Kb, VTb);

  if (ws_size >= need) {
    flash_kernel<2><<<dim3(256, 2), 512, 0, stream>>>(Qb, Kb, VTb, nullptr, Opart, MLbuf);
    combine_kernel<<<2560, 256, 0, stream>>>(Opart, MLbuf, AOb);
  } else {
    flash_kernel<1><<<dim3(256, 1), 512, 0, stream>>>(Qb, Kb, VTb, AOb, nullptr, nullptr);
  }
  gemm_out_kernel<<<dim3(10, 32), 256, 0, stream>>>(AOb, Wt + 3 * WSZ, out, out_b, hs);
}